// Round 11
// baseline (163.983 us; speedup 1.0000x reference)
//
#include <hip/hip_runtime.h>
#include <math.h>

#define GAMMA 0.25f
constexpr int B_ = 8, Q_ = 64, N_ = 8192, K_ = 512, C_ = 256;

typedef __attribute__((ext_vector_type(8))) short bf16x8;
typedef __attribute__((ext_vector_type(4))) float f32x4;

static __device__ inline short f2bf(float x) {   // RNE float->bf16 bits
    union { float f; unsigned u; } v; v.f = x;
    unsigned r = (v.u + 0x7fffu + ((v.u >> 16) & 1u)) >> 16;
    return (short)r;
}
// pack trunc(lo),trunc(hi) bf16 into one dword via v_perm_b32 (1 instr)
static __device__ inline unsigned pack2(float lo, float hi) {
    return __builtin_amdgcn_perm(__float_as_uint(hi), __float_as_uint(lo), 0x07060302u);
}

// ---------------------------------------------------------------------------
// Grid = 2048. Even bid -> CE (1024 blocks x 64 items). Odd bid -> VQ
// (1024 blocks x 64 items, waves codeword-split: wave w owns cw [128w,128w+128),
// 8 iterations of 8 MFMAs). Interleaved so both kinds co-reside per CU.
// ---------------------------------------------------------------------------
__global__ __launch_bounds__(256, 2) void fused_kernel(
    const float* __restrict__ ze, const float* __restrict__ emb,
    const float* __restrict__ qp, const int* __restrict__ tgt,
    float* __restrict__ out)
{
    __shared__ float smem[512];   // 2 KB. CE: f32x4 part[64]. VQ: e2[512] then min[256].
    const int bid  = blockIdx.x;
    const int tid  = threadIdx.x;
    const int lane = tid & 63;
    const int w    = tid >> 6;

    if ((bid & 1) == 0) {
        // =============================== CE ===============================
        const int cid  = bid >> 1;                    // 0..1023
        const int base = cid * 64;
        const int b    = base >> 13;
        const int n0   = base & (N_ - 1);
        const int g    = lane & 15;                   // item group (4 items)
        const int c0   = lane >> 4;                   // class subgroup
        const float* qpn = qp + (size_t)b * C_ * N_ + n0 + g * 4;

        f32x4 acc = {0.f, 0.f, 0.f, 0.f};
        const int cbase = w * 64 + c0 * 16;
        #pragma unroll
        for (int j = 0; j < 16; ++j) {
            const float4 v = *(const float4*)(qpn + (size_t)(cbase + j) * N_);
            acc[0] += __expf(v.x); acc[1] += __expf(v.y);
            acc[2] += __expf(v.z); acc[3] += __expf(v.w);
        }
        #pragma unroll
        for (int r = 0; r < 4; ++r) {                 // sum over c0 (lane bits 4,5)
            acc[r] += __shfl_xor(acc[r], 16, 64);
            acc[r] += __shfl_xor(acc[r], 32, 64);
        }
        f32x4* part = (f32x4*)smem;                   // part[w*16+g]
        if (c0 == 0) part[w * 16 + g] = acc;
        __syncthreads();

        if (w == 0) {
            float loss = 0.f;
            if (lane < 16) {                          // g = lane
                const f32x4 tot = (part[g] + part[16 + g]) +
                                  (part[32 + g] + part[48 + g]);
                #pragma unroll
                for (int j2 = 0; j2 < 4; ++j2) {
                    const int t = tgt[base + g * 4 + j2];
                    const float xt = qpn[(size_t)t * N_ + j2];
                    loss += __logf(tot[j2]) - xt;
                }
            }
            #pragma unroll
            for (int off = 32; off > 0; off >>= 1) loss += __shfl_down(loss, off, 64);
            if (lane == 0) atomicAdd(out, loss);
        }
    } else {
        // =============================== VQ ===============================
        const int vid  = bid >> 1;                    // 0..1023
        const int n16  = lane & 15;
        const int quad = lane >> 4;
        const int ib0  = vid * 64;                    // 64-aligned => b uniform
        const int b    = ib0 >> 13;
        const int n0   = ib0 & (N_ - 1);
        const float* zb = ze + (size_t)b * Q_ * N_;

        // e2 prologue into LDS (all 512 codewords; emb is L2-hot).
        for (int r = tid; r < K_; r += 256) {
            const float4* er = (const float4*)(emb + r * Q_);
            float s0 = 0.f, s1 = 0.f;
            #pragma unroll
            for (int i = 0; i < 16; i += 2) {
                const float4 a = er[i], c = er[i + 1];
                s0 = fmaf(a.x, a.x, fmaf(a.y, a.y, fmaf(a.z, a.z, fmaf(a.w, a.w, s0))));
                s1 = fmaf(c.x, c.x, fmaf(c.y, c.y, fmaf(c.z, c.z, fmaf(c.w, c.w, s1))));
            }
            smem[r] = s0 + s1;
        }

        // A fragments: all 4 item-tiles (64 items) per wave, bf16(-2z) RNE.
        // zsq (fp32, exact) is only consumed from wave 0's lanes.
        bf16x8 afrag[4][2];
        float zsq = 0.f;
        #pragma unroll
        for (int u = 0; u < 4; ++u) {
            const int nn = n0 + u * 16 + n16;
            #pragma unroll
            for (int s = 0; s < 2; ++s) {
                #pragma unroll
                for (int j = 0; j < 8; ++j) {
                    const int q = s * 32 + quad * 8 + j;
                    const float x = zb[(size_t)q * N_ + nn];
                    zsq = fmaf(x, x, zsq);
                    afrag[u][s][j] = f2bf(-2.f * x);  // exact pow2 scale
                }
            }
        }
        __syncthreads();                              // e2 ready

        f32x4 best[4];
        #pragma unroll
        for (int u = 0; u < 4; ++u) best[u] = (f32x4){1e30f, 1e30f, 1e30f, 1e30f};

        // B rows for this wave: cw = 128w + 16t + n16, 8 tiles.
        const float* ebase = emb + (w * 128 + n16) * Q_ + quad * 8;
        float4 c0a = *(const float4*)(ebase);
        float4 c0b = *(const float4*)(ebase + 4);
        float4 c1a = *(const float4*)(ebase + 32);
        float4 c1b = *(const float4*)(ebase + 36);

        for (int t = 0; t < 8; ++t) {
            float4 x0a = c0a, x0b = c0b, x1a = c1a, x1b = c1b;
            if (t < 7) {                              // wave-uniform prefetch
                const float* np = ebase + (t + 1) * 16 * Q_;
                x0a = *(const float4*)(np);
                x0b = *(const float4*)(np + 4);
                x1a = *(const float4*)(np + 32);
                x1b = *(const float4*)(np + 36);
            }
            const float p = smem[w * 128 + t * 16 + n16];  // e2, off critical path

            union { bf16x8 v; unsigned u[4]; } B0, B1;
            B0.u[0] = pack2(c0a.x, c0a.y); B0.u[1] = pack2(c0a.z, c0a.w);
            B0.u[2] = pack2(c0b.x, c0b.y); B0.u[3] = pack2(c0b.z, c0b.w);
            B1.u[0] = pack2(c1a.x, c1a.y); B1.u[1] = pack2(c1a.z, c1a.w);
            B1.u[2] = pack2(c1b.x, c1b.y); B1.u[3] = pack2(c1b.z, c1b.w);

            const f32x4 ce2 = {p, p, p, p};
            #pragma unroll
            for (int u = 0; u < 4; ++u) {             // 4 independent MFMA chains
                f32x4 a = __builtin_amdgcn_mfma_f32_16x16x32_bf16(afrag[u][0], B0.v, ce2, 0, 0, 0);
                a       = __builtin_amdgcn_mfma_f32_16x16x32_bf16(afrag[u][1], B1.v, a,   0, 0, 0);
                #pragma unroll
                for (int r = 0; r < 4; ++r) best[u][r] = fminf(best[u][r], a[r]);
            }
            c0a = x0a; c0b = x0b; c1a = x1a; c1b = x1b;
        }

        // min over this wave's 16 cw columns (lane bits 0..3)
        #pragma unroll
        for (int m = 1; m < 16; m <<= 1) {
            #pragma unroll
            for (int u = 0; u < 4; ++u) {
                #pragma unroll
                for (int r = 0; r < 4; ++r)
                    best[u][r] = fminf(best[u][r], __shfl_xor(best[u][r], m, 64));
            }
        }

        __syncthreads();                              // all waves done reading e2
        if (n16 == 0) {                               // lanes 0,16,32,48
            #pragma unroll
            for (int u = 0; u < 4; ++u) {
                #pragma unroll
                for (int r = 0; r < 4; ++r)           // item = u*16 + quad*4 + r
                    smem[w * 64 + u * 16 + quad * 4 + r] = best[u][r];
            }
        }
        __syncthreads();

        if (w == 0) {
            const float mn = fminf(fminf(smem[lane], smem[64 + lane]),
                                   fminf(smem[128 + lane], smem[192 + lane]));
            float val = 1.25f * (mn + zsq);           // wave-0 zsq covers all 64 items
            #pragma unroll
            for (int off = 32; off > 0; off >>= 1) val += __shfl_down(val, off, 64);
            if (lane == 0) atomicAdd(out, val);
        }
    }
}

extern "C" void kernel_launch(void* const* d_in, const int* in_sizes, int n_in,
                              void* d_out, int out_size, void* d_ws, size_t ws_size,
                              hipStream_t stream) {
    const float* ze  = (const float*)d_in[0];
    const float* emb = (const float*)d_in[1];
    const float* qp  = (const float*)d_in[2];
    const int*   tgt = (const int*)d_in[3];
    float* out = (float*)d_out;

    hipMemsetAsync(out, 0, sizeof(float), stream);

    fused_kernel<<<2048, 256, 0, stream>>>(ze, emb, qp, tgt, out);
}

// Round 12
// 155.293 us; speedup vs baseline: 1.0560x; 1.0560x over previous
//
#include <hip/hip_runtime.h>
#include <math.h>

#define GAMMA 0.25f
constexpr int B_ = 8, Q_ = 64, N_ = 8192, K_ = 512, C_ = 256;

typedef __attribute__((ext_vector_type(8))) short bf16x8;
typedef __attribute__((ext_vector_type(4))) float f32x4;

static __device__ inline short f2bf(float x) {   // RNE float->bf16 bits
    union { float f; unsigned u; } v; v.f = x;
    unsigned r = (v.u + 0x7fffu + ((v.u >> 16) & 1u)) >> 16;
    return (short)r;
}
// pack trunc(lo),trunc(hi) bf16 into one dword via v_perm_b32 (1 instr)
static __device__ inline unsigned pack2(float lo, float hi) {
    return __builtin_amdgcn_perm(__float_as_uint(hi), __float_as_uint(lo), 0x07060302u);
}

// ---------------------------------------------------------------------------
// Grid = 2048, RANGE split (not parity: parity confines a leg to half the
// XCDs since wg->XCD is round-robin by blockIdx). bid<1024 -> CE block
// (64 items); bid>=1024 -> VQ block (64 items, waves codeword-split, ALL
// 8 B-tiles issued upfront so the MFMA loop has zero memory stalls).
// ---------------------------------------------------------------------------
__global__ __launch_bounds__(256) void fused_kernel(
    const float* __restrict__ ze, const float* __restrict__ emb,
    const float* __restrict__ qp, const int* __restrict__ tgt,
    float* __restrict__ out)
{
    __shared__ float smem[512];   // CE: f32x4 part[64] (1 KB). VQ: e2[512] then min[256].
    const int bid  = blockIdx.x;
    const int tid  = threadIdx.x;
    const int lane = tid & 63;
    const int w    = tid >> 6;

    if (bid < 1024) {
        // =============================== CE ===============================
        const int base = bid * 64;                    // flat item base
        const int b    = base >> 13;
        const int n0   = base & (N_ - 1);
        const int g    = lane & 15;                   // item group (4 items)
        const int c0   = lane >> 4;                   // class subgroup
        const float* qpn = qp + (size_t)b * C_ * N_ + n0 + g * 4;

        f32x4 acc = {0.f, 0.f, 0.f, 0.f};
        const int cbase = w * 64 + c0 * 16;
        #pragma unroll
        for (int j = 0; j < 16; ++j) {                // 16 independent 16B loads
            const float4 v = *(const float4*)(qpn + (size_t)(cbase + j) * N_);
            acc[0] += __expf(v.x); acc[1] += __expf(v.y);
            acc[2] += __expf(v.z); acc[3] += __expf(v.w);
        }
        #pragma unroll
        for (int r = 0; r < 4; ++r) {                 // sum over c0 (lane bits 4,5)
            acc[r] += __shfl_xor(acc[r], 16, 64);
            acc[r] += __shfl_xor(acc[r], 32, 64);
        }
        f32x4* part = (f32x4*)smem;                   // part[w*16+g]
        if (c0 == 0) part[w * 16 + g] = acc;
        __syncthreads();

        if (w == 0) {
            float loss = 0.f;
            if (lane < 16) {                          // g = lane
                const f32x4 tot = (part[g] + part[16 + g]) +
                                  (part[32 + g] + part[48 + g]);
                #pragma unroll
                for (int j2 = 0; j2 < 4; ++j2) {
                    const int t = tgt[base + g * 4 + j2];
                    const float xt = qpn[(size_t)t * N_ + j2];
                    loss += __logf(tot[j2]) - xt;
                }
            }
            #pragma unroll
            for (int off = 32; off > 0; off >>= 1) loss += __shfl_down(loss, off, 64);
            if (lane == 0) atomicAdd(out, loss);
        }
    } else {
        // =============================== VQ ===============================
        const int vid  = bid - 1024;                  // 0..1023
        const int n16  = lane & 15;
        const int quad = lane >> 4;
        const int ib0  = vid * 64;                    // 64-aligned => b uniform
        const int b    = ib0 >> 13;
        const int n0   = ib0 & (N_ - 1);
        const float* zb = ze + (size_t)b * Q_ * N_;

        // ---- A phase: 4 item-tiles, bf16(-2z) RNE + exact fp32 sum(z^2) ----
        bf16x8 afrag[4][2];
        float zsq = 0.f;
        #pragma unroll
        for (int u = 0; u < 4; ++u) {
            const int nn = n0 + u * 16 + n16;
            #pragma unroll
            for (int s = 0; s < 2; ++s) {
                #pragma unroll
                for (int j = 0; j < 8; ++j) {
                    const int q = s * 32 + quad * 8 + j;
                    const float x = zb[(size_t)q * N_ + nn];
                    zsq = fmaf(x, x, zsq);
                    afrag[u][s][j] = f2bf(-2.f * x);  // exact pow2 scale
                }
            }
        }

        // ---- B phase: issue ALL 8 tiles (32 independent float4/lane) ----
        const float* ebase = emb + (w * 128 + n16) * Q_ + quad * 8;
        float4 Bf[8][4];
        #pragma unroll
        for (int t = 0; t < 8; ++t) {
            const float* p = ebase + t * 16 * Q_;
            Bf[t][0] = *(const float4*)(p);
            Bf[t][1] = *(const float4*)(p + 4);
            Bf[t][2] = *(const float4*)(p + 32);
            Bf[t][3] = *(const float4*)(p + 36);
        }

        // ---- e2 prologue into LDS (loads fill the B-latency shadow) ----
        for (int r = tid; r < K_; r += 256) {
            const float4* er = (const float4*)(emb + r * Q_);
            float s0 = 0.f, s1 = 0.f;
            #pragma unroll
            for (int i = 0; i < 16; i += 2) {
                const float4 a = er[i], c = er[i + 1];
                s0 = fmaf(a.x, a.x, fmaf(a.y, a.y, fmaf(a.z, a.z, fmaf(a.w, a.w, s0))));
                s1 = fmaf(c.x, c.x, fmaf(c.y, c.y, fmaf(c.z, c.z, fmaf(c.w, c.w, s1))));
            }
            smem[r] = s0 + s1;
        }
        __syncthreads();   // drains all outstanding loads once; e2 ready

        // ---- compute: 8 tiles back-to-back, zero memory stalls ----
        f32x4 best[4];
        #pragma unroll
        for (int u = 0; u < 4; ++u) best[u] = (f32x4){1e30f, 1e30f, 1e30f, 1e30f};

        #pragma unroll
        for (int t = 0; t < 8; ++t) {
            union { bf16x8 v; unsigned u[4]; } B0, B1;
            B0.u[0] = pack2(Bf[t][0].x, Bf[t][0].y); B0.u[1] = pack2(Bf[t][0].z, Bf[t][0].w);
            B0.u[2] = pack2(Bf[t][1].x, Bf[t][1].y); B0.u[3] = pack2(Bf[t][1].z, Bf[t][1].w);
            B1.u[0] = pack2(Bf[t][2].x, Bf[t][2].y); B1.u[1] = pack2(Bf[t][2].z, Bf[t][2].w);
            B1.u[2] = pack2(Bf[t][3].x, Bf[t][3].y); B1.u[3] = pack2(Bf[t][3].z, Bf[t][3].w);

            const float p = smem[w * 128 + t * 16 + n16];  // broadcast ds_read
            const f32x4 ce2 = {p, p, p, p};
            #pragma unroll
            for (int u = 0; u < 4; ++u) {             // 4 independent MFMA chains
                f32x4 a = __builtin_amdgcn_mfma_f32_16x16x32_bf16(afrag[u][0], B0.v, ce2, 0, 0, 0);
                a       = __builtin_amdgcn_mfma_f32_16x16x32_bf16(afrag[u][1], B1.v, a,   0, 0, 0);
                #pragma unroll
                for (int r = 0; r < 4; ++r) best[u][r] = fminf(best[u][r], a[r]);
            }
        }

        // min over this wave's 16 cw columns (lane bits 0..3)
        #pragma unroll
        for (int m = 1; m < 16; m <<= 1) {
            #pragma unroll
            for (int u = 0; u < 4; ++u) {
                #pragma unroll
                for (int r = 0; r < 4; ++r)
                    best[u][r] = fminf(best[u][r], __shfl_xor(best[u][r], m, 64));
            }
        }

        __syncthreads();                              // all waves done reading e2
        if (n16 == 0) {                               // lanes 0,16,32,48
            #pragma unroll
            for (int u = 0; u < 4; ++u) {
                #pragma unroll
                for (int r = 0; r < 4; ++r)           // item = u*16 + quad*4 + r
                    smem[w * 64 + u * 16 + quad * 4 + r] = best[u][r];
            }
        }
        __syncthreads();

        if (w == 0) {
            const float mn = fminf(fminf(smem[lane], smem[64 + lane]),
                                   fminf(smem[128 + lane], smem[192 + lane]));
            float val = 1.25f * (mn + zsq);           // wave-0 zsq covers all 64 items
            #pragma unroll
            for (int off = 32; off > 0; off >>= 1) val += __shfl_down(val, off, 64);
            if (lane == 0) atomicAdd(out, val);
        }
    }
}

extern "C" void kernel_launch(void* const* d_in, const int* in_sizes, int n_in,
                              void* d_out, int out_size, void* d_ws, size_t ws_size,
                              hipStream_t stream) {
    const float* ze  = (const float*)d_in[0];
    const float* emb = (const float*)d_in[1];
    const float* qp  = (const float*)d_in[2];
    const int*   tgt = (const int*)d_in[3];
    float* out = (float*)d_out;

    hipMemsetAsync(out, 0, sizeof(float), stream);

    fused_kernel<<<2048, 256, 0, stream>>>(ze, emb, qp, tgt, out);
}